// Round 1
// 139.671 us; speedup vs baseline: 1.0167x; 1.0167x over previous
//
#include <hip/hip_runtime.h>
#include <hip/hip_bf16.h>

// ============================================================================
// indices ∈ [0,64) => backbone + theta have only 64 distinct rows. Compute
// per-class (7 MB, L2-resident), bucket batches by class, run only the tiny
// per-batch MLPs with class-shared weights.
// R5: K3 rewrite — ALL per-class weights (e 5392 + f 21768 = 27160 fl =
// 108.6KB) resident in dynamic LDS (143.4KB total with acts). No in-loop
// staging, 6 barriers/pass (was ~15), f-L2 full-K in one sweep (no quarter
// cycling), balanced interleaved 32-block slicing. 1 block/CU (grid==256)
// unchanged.
// ============================================================================

#define LEAKY 0.2f
#define NCLS 64
#define B_TOT 8192
#define NSLICE 4

// theta_e (per class, 5456 fl): W1e[0,128) b1e[128,192) W2e[192,4288)
//   b2e[4288,4352) W3e[4352,5376) b3e[5376,5392)
// theta_f (per class, 21768 fl): W1f[0,4096) b1f[4096,4224) W2f[4224,20608)
//   b2f[20608,20736) W3f[20736,21760) b3f[21760,21768)

__device__ __forceinline__ float lrelu(float x) { return x >= 0.f ? x : LEAKY * x; }

// ---------------------------------------------------------------------------
// K1: blocks 0..63: fused backbone for class c. block 64: bucket.
// 1024 threads.
// ---------------------------------------------------------------------------
__global__ __launch_bounds__(1024) void backbone_bucket_kernel(
    const float* __restrict__ maps,
    const float* __restrict__ fc1_w, const float* __restrict__ fc1_b,
    const float* __restrict__ fc2_w, const float* __restrict__ fc2_b,
    const float* __restrict__ fc3_w, const float* __restrict__ fc3_b,
    const float* __restrict__ bn_w,  const float* __restrict__ bn_b,
    float* __restrict__ z,
    const int* __restrict__ idx, int* __restrict__ counts,
    int* __restrict__ offsets, int* __restrict__ perm)
{
    __shared__ float m[1024];
    __shared__ float red[1024];
    __shared__ float h1[256];
    __shared__ float h2[128];
    __shared__ float h3[128];
    __shared__ int cnt[16][64];
    __shared__ int wcur[16][64];

    const int t = threadIdx.x;

    if (blockIdx.x == 64) {
        // ---------------- bucket ----------------
        const int w = t >> 6;
        cnt[w][t & 63] = 0;
        __syncthreads();
        int my[8];
#pragma unroll
        for (int r = 0; r < 8; ++r) {
            my[r] = idx[r * 1024 + t];
            atomicAdd(&cnt[w][my[r]], 1);
        }
        __syncthreads();
        if (t < 64) {
            int run = 0;
#pragma unroll
            for (int w2 = 0; w2 < 16; ++w2) {
                const int v = cnt[w2][t];
                wcur[w2][t] = run;
                run += v;
            }
            counts[t] = run;
            int x = run;
            for (int d = 1; d < 64; d <<= 1) {
                const int y = __shfl_up(x, d, 64);
                if (t >= d) x += y;
            }
            const int basec = x - run;
            offsets[t] = basec;
#pragma unroll
            for (int w2 = 0; w2 < 16; ++w2) wcur[w2][t] += basec;
        }
        __syncthreads();
#pragma unroll
        for (int r = 0; r < 8; ++r) {
            const int p = atomicAdd(&wcur[w][my[r]], 1);
            perm[p] = r * 1024 + t;
        }
        return;
    }

    // ---------------- backbone for class c ----------------
    const int c = blockIdx.x;
    m[t] = maps[(size_t)c * 1024 + t];
    __syncthreads();

    // fc1: 1024 -> 256 (leaky); o = t&255, 4 K-slices of 256
    {
        const int o = t & 255, ks = t >> 8;
        const float* wp = fc1_w + o;
        float acc = 0.f;
#pragma unroll 8
        for (int i = 0; i < 256; ++i) {
            const int k = ks * 256 + i;
            acc += m[k] * wp[(size_t)k * 256];
        }
        red[t] = acc;
    }
    __syncthreads();
    if (t < 256)
        h1[t] = lrelu(fc1_b[t] + red[t] + red[256 + t] + red[512 + t] + red[768 + t]);
    __syncthreads();
    // fc2: 256 -> 128 (leaky); o = t&127, 8 K-slices of 32
    {
        const int o = t & 127, ks = t >> 7;
        float acc = 0.f;
#pragma unroll
        for (int i = 0; i < 32; ++i) {
            const int k = ks * 32 + i;
            acc += h1[k] * fc2_w[k * 128 + o];
        }
        red[t] = acc;
    }
    __syncthreads();
    if (t < 128) {
        float a = fc2_b[t];
#pragma unroll
        for (int r = 0; r < 8; ++r) a += red[r * 128 + t];
        h2[t] = lrelu(a);
    }
    __syncthreads();
    // fc3: 128 -> 128 (leaky); 8 K-slices of 16
    {
        const int o = t & 127, ks = t >> 7;
        float acc = 0.f;
#pragma unroll
        for (int i = 0; i < 16; ++i) {
            const int k = ks * 16 + i;
            acc += h2[k] * fc3_w[k * 128 + o];
        }
        red[t] = acc;
    }
    __syncthreads();
    if (t < 128) {
        float a = fc3_b[t];
#pragma unroll
        for (int r = 0; r < 8; ++r) a += red[r * 128 + t];
        h3[t] = lrelu(a);
    }
    __syncthreads();
    // bn: 128 -> 32 (no act); o = t&31, 32 K-slices of 4
    {
        const int o = t & 31, ks = t >> 5;
        float acc = 0.f;
#pragma unroll
        for (int i = 0; i < 4; ++i) {
            const int k = ks * 4 + i;
            acc += h3[k] * bn_w[k * 32 + o];
        }
        red[t] = acc;
    }
    __syncthreads();
    if (t < 32) {
        float a = bn_b[t];
#pragma unroll
        for (int r = 0; r < 32; ++r) a += red[r * 32 + t];
        z[c * 32 + t] = a;
    }
}

// ---------------------------------------------------------------------------
// K2: theta, grid (107, 8): block owns 256 cols x 8 classes. Weights in regs.
// ---------------------------------------------------------------------------
__global__ __launch_bounds__(256) void theta_kernel(
    const float* __restrict__ z,
    const float* __restrict__ e_w, const float* __restrict__ e_b,
    const float* __restrict__ f_w, const float* __restrict__ f_b,
    float* __restrict__ th_e, float* __restrict__ th_f)
{
    __shared__ __align__(16) float zl[2048];
    const int t = threadIdx.x;
    ((float4*)zl)[t]       = ((const float4*)z)[t];
    ((float4*)zl)[t + 256] = ((const float4*)z)[t + 256];
    __syncthreads();

    int j = blockIdx.x * 256 + t;
    const int cbase = blockIdx.y * 8;
    const float* wbase;
    float* op;
    int stride;
    float bias;
    if (j < 5456) {
        wbase = e_w + j; bias = e_b[j]; op = th_e + j; stride = 5456;
    } else {
        const int jj = j - 5456;
        if (jj >= 21768) return;
        wbase = f_w + jj; bias = f_b[jj]; op = th_f + jj; stride = 21768;
    }
    float wk[32];
#pragma unroll
    for (int k = 0; k < 32; ++k) wk[k] = wbase[(size_t)k * stride];

#pragma unroll
    for (int cc = 0; cc < 8; cc += 4) {
        const int c0 = cbase + cc;
        float a0 = bias, a1 = bias, a2 = bias, a3 = bias;
#pragma unroll
        for (int k4 = 0; k4 < 8; ++k4) {
            const float4 z0 = *(const float4*)&zl[(c0 + 0) * 32 + k4 * 4];
            const float4 z1 = *(const float4*)&zl[(c0 + 1) * 32 + k4 * 4];
            const float4 z2 = *(const float4*)&zl[(c0 + 2) * 32 + k4 * 4];
            const float4 z3 = *(const float4*)&zl[(c0 + 3) * 32 + k4 * 4];
            const float w0 = wk[k4 * 4], w1 = wk[k4 * 4 + 1];
            const float w2 = wk[k4 * 4 + 2], w3 = wk[k4 * 4 + 3];
            a0 += z0.x * w0 + z0.y * w1 + z0.z * w2 + z0.w * w3;
            a1 += z1.x * w0 + z1.y * w1 + z1.z * w2 + z1.w * w3;
            a2 += z2.x * w0 + z2.y * w1 + z2.z * w2 + z2.w * w3;
            a3 += z3.x * w0 + z3.y * w1 + z3.z * w2 + z3.w * w3;
        }
        op[(size_t)(c0 + 0) * stride] = a0;
        op[(size_t)(c0 + 1) * stride] = a1;
        op[(size_t)(c0 + 2) * stride] = a2;
        op[(size_t)(c0 + 3) * stride] = a3;
    }
}

// ---------------------------------------------------------------------------
// K3: func v5. grid (64, 4), 512 thr (8 waves). ALL weights LDS-resident:
//   wE[5392] | wF[21768] | actA[4352] | actB[4352]  = 35864 fl = 143456 B
// dynamic LDS (opt-in). Staged ONCE per block; pass loop has 6 barriers and
// zero staging. Slices take interleaved 32-batch blocks (s, s+4, ...).
//   e: vb = t&63 (32 batches x {S,G}), ge = t>>6 (8 groups x 8 cols)
//   f: b = t&31, gf = t>>5 (16 groups x 8 cols)
// ---------------------------------------------------------------------------
#define ESTRIDE 68   // 17 float4s, odd -> conflict-free across 64 vbatches
#define FSTRIDE 132  // 33 float4s, odd

#define K3_LDS_FLOATS 35864
#define K3_LDS_BYTES  (K3_LDS_FLOATS * 4)

__global__ __launch_bounds__(512) void func_kernel(
    const float* __restrict__ states,
    const float* __restrict__ th_e_all, const float* __restrict__ th_f_all,
    const int* __restrict__ counts, const int* __restrict__ offsets,
    const int* __restrict__ perm, float* __restrict__ out)
{
    extern __shared__ float smem[];
    float* wE   = smem;            // 5392: full theta_e
    float* wF   = smem + 5392;     // 21768: full theta_f
    float* actA = smem + 27160;    // 4352
    float* actB = smem + 31512;    // 4352

    const int c = blockIdx.x;
    const int s = blockIdx.y;
    const int nb   = counts[c];
    const int base = offsets[c];
    const int nblk = (nb + 31) >> 5;                         // total 32-blocks
    const int npass = (nblk > s) ? ((nblk - 1 - s) / NSLICE + 1) : 0;
    if (npass == 0) return;

    const float* te = th_e_all + (size_t)c * 5456;
    const float* tf = th_f_all + (size_t)c * 21768;

    const int t  = threadIdx.x;
    const int b  = t & 31;           // batch slot (both views)
    const int ve = (t >> 5) & 1;     // e: S/G select
    const int vb = t & 63;           // e virtual batch
    const int ge = t >> 6;           // e col group (wave-uniform)
    const int gf = t >> 5;           // f col group (2 per wave)
    const int cole = ge * 8;
    const int colf = gf * 8;
    const int eoff = vb * ESTRIDE;
    const int foff = b * FSTRIDE;

    // ---- stage ALL weights once ----
    for (int j = t * 4; j < 5392; j += 2048)
        *(float4*)&wE[j] = *(const float4*)&te[j];
    for (int j = t * 4; j < 21768; j += 2048)
        *(float4*)&wF[j] = *(const float4*)&tf[j];

    for (int p = 0; p < npass; ++p) {
        __syncthreads();   // staging visible / prev-pass f-L3 actA reads done

        const int kk = ((p * NSLICE + s) << 5) + b;   // batch idx within class
        const bool valid = kk < nb;
        const int bi = valid ? perm[base + kk] : 0;
        const float2 sv = *(const float2*)&states[(size_t)bi * 4 + 2 * ve];

        // ---- e-L1: 2 -> 64 (leaky) ----
        {
            const float4 wa0 = *(const float4*)&wE[cole];
            const float4 wa1 = *(const float4*)&wE[cole + 4];
            const float4 wb0 = *(const float4*)&wE[64 + cole];
            const float4 wb1 = *(const float4*)&wE[64 + cole + 4];
            const float4 bb0 = *(const float4*)&wE[128 + cole];
            const float4 bb1 = *(const float4*)&wE[128 + cole + 4];
            float4 o0, o1;
            o0.x = lrelu(sv.x * wa0.x + sv.y * wb0.x + bb0.x);
            o0.y = lrelu(sv.x * wa0.y + sv.y * wb0.y + bb0.y);
            o0.z = lrelu(sv.x * wa0.z + sv.y * wb0.z + bb0.z);
            o0.w = lrelu(sv.x * wa0.w + sv.y * wb0.w + bb0.w);
            o1.x = lrelu(sv.x * wa1.x + sv.y * wb1.x + bb1.x);
            o1.y = lrelu(sv.x * wa1.y + sv.y * wb1.y + bb1.y);
            o1.z = lrelu(sv.x * wa1.z + sv.y * wb1.z + bb1.z);
            o1.w = lrelu(sv.x * wa1.w + sv.y * wb1.w + bb1.w);
            *(float4*)&actA[eoff + cole]     = o0;
            *(float4*)&actA[eoff + cole + 4] = o1;
        }
        __syncthreads();

        // ---- e-L2: 64 -> 64 (leaky) ----
        {
            float acc[8] = {0, 0, 0, 0, 0, 0, 0, 0};
#pragma unroll 4
            for (int i4 = 0; i4 < 16; ++i4) {
                const float4 y4 = *(const float4*)&actA[eoff + i4 * 4];
#pragma unroll
                for (int u = 0; u < 4; ++u) {
                    const int row = 192 + (i4 * 4 + u) * 64 + cole;
                    const float4 wA = *(const float4*)&wE[row];
                    const float4 wB = *(const float4*)&wE[row + 4];
                    const float yv = (&y4.x)[u];
                    acc[0] += yv * wA.x; acc[1] += yv * wA.y;
                    acc[2] += yv * wA.z; acc[3] += yv * wA.w;
                    acc[4] += yv * wB.x; acc[5] += yv * wB.y;
                    acc[6] += yv * wB.z; acc[7] += yv * wB.w;
                }
            }
            const float4 bA = *(const float4*)&wE[4288 + cole];
            const float4 bB = *(const float4*)&wE[4288 + cole + 4];
            float4 o0, o1;
            o0.x = lrelu(acc[0] + bA.x); o0.y = lrelu(acc[1] + bA.y);
            o0.z = lrelu(acc[2] + bA.z); o0.w = lrelu(acc[3] + bA.w);
            o1.x = lrelu(acc[4] + bB.x); o1.y = lrelu(acc[5] + bB.y);
            o1.z = lrelu(acc[6] + bB.z); o1.w = lrelu(acc[7] + bB.w);
            *(float4*)&actB[eoff + cole]     = o0;
            *(float4*)&actB[eoff + cole + 4] = o1;
        }
        __syncthreads();

        // ---- e-L3: 64 -> 16 (no act) -> zf (f-view of actA) ----
        {
            const int col3 = ge * 2;
            float a0 = 0.f, a1 = 0.f;
#pragma unroll 4
            for (int i4 = 0; i4 < 16; ++i4) {
                const float4 y4 = *(const float4*)&actB[eoff + i4 * 4];
#pragma unroll
                for (int u = 0; u < 4; ++u) {
                    const int i = i4 * 4 + u;
                    const float yv = (&y4.x)[u];
                    const float2 w2 = *(const float2*)&wE[4352 + i * 16 + col3];
                    a0 += yv * w2.x;
                    a1 += yv * w2.y;
                }
            }
            a0 += wE[5376 + col3];
            a1 += wE[5376 + col3 + 1];
            actA[foff + ve * 16 + col3]     = a0;
            actA[foff + ve * 16 + col3 + 1] = a1;
        }
        __syncthreads();

        // ---- f-L1: 32 -> 128 (leaky) ----
        {
            float acc[8] = {0, 0, 0, 0, 0, 0, 0, 0};
#pragma unroll
            for (int i4 = 0; i4 < 8; ++i4) {
                const float4 y4 = *(const float4*)&actA[foff + i4 * 4];
#pragma unroll
                for (int u = 0; u < 4; ++u) {
                    const int row = (i4 * 4 + u) * 128 + colf;
                    const float4 wA = *(const float4*)&wF[row];
                    const float4 wB = *(const float4*)&wF[row + 4];
                    const float yv = (&y4.x)[u];
                    acc[0] += yv * wA.x; acc[1] += yv * wA.y;
                    acc[2] += yv * wA.z; acc[3] += yv * wA.w;
                    acc[4] += yv * wB.x; acc[5] += yv * wB.y;
                    acc[6] += yv * wB.z; acc[7] += yv * wB.w;
                }
            }
            const float4 bA = *(const float4*)&wF[4096 + colf];
            const float4 bB = *(const float4*)&wF[4096 + colf + 4];
            float4 o0, o1;
            o0.x = lrelu(acc[0] + bA.x); o0.y = lrelu(acc[1] + bA.y);
            o0.z = lrelu(acc[2] + bA.z); o0.w = lrelu(acc[3] + bA.w);
            o1.x = lrelu(acc[4] + bB.x); o1.y = lrelu(acc[5] + bB.y);
            o1.z = lrelu(acc[6] + bB.z); o1.w = lrelu(acc[7] + bB.w);
            *(float4*)&actB[foff + colf]     = o0;
            *(float4*)&actB[foff + colf + 4] = o1;
        }
        __syncthreads();

        // ---- f-L2: 128 -> 128 (leaky), full K, weights resident ----
        {
            float acc[8] = {0, 0, 0, 0, 0, 0, 0, 0};
#pragma unroll 4
            for (int i4 = 0; i4 < 32; ++i4) {
                const float4 y4 = *(const float4*)&actB[foff + i4 * 4];
#pragma unroll
                for (int u = 0; u < 4; ++u) {
                    const int row = 4224 + (i4 * 4 + u) * 128 + colf;
                    const float4 wA = *(const float4*)&wF[row];
                    const float4 wB = *(const float4*)&wF[row + 4];
                    const float yv = (&y4.x)[u];
                    acc[0] += yv * wA.x; acc[1] += yv * wA.y;
                    acc[2] += yv * wA.z; acc[3] += yv * wA.w;
                    acc[4] += yv * wB.x; acc[5] += yv * wB.y;
                    acc[6] += yv * wB.z; acc[7] += yv * wB.w;
                }
            }
            const float4 bA = *(const float4*)&wF[20608 + colf];
            const float4 bB = *(const float4*)&wF[20608 + colf + 4];
            float4 o0, o1;
            o0.x = lrelu(acc[0] + bA.x); o0.y = lrelu(acc[1] + bA.y);
            o0.z = lrelu(acc[2] + bA.z); o0.w = lrelu(acc[3] + bA.w);
            o1.x = lrelu(acc[4] + bB.x); o1.y = lrelu(acc[5] + bB.y);
            o1.z = lrelu(acc[6] + bB.z); o1.w = lrelu(acc[7] + bB.w);
            *(float4*)&actA[foff + colf]     = o0;
            *(float4*)&actA[foff + colf + 4] = o1;
        }
        __syncthreads();

        // ---- f-L3: 128 -> 8 (no act) + sin/cos ----
        if (gf < 8) {
            float a = 0.f;
#pragma unroll 8
            for (int i4 = 0; i4 < 32; ++i4) {
                const float4 y4 = *(const float4*)&actA[foff + i4 * 4];
#pragma unroll
                for (int u = 0; u < 4; ++u)
                    a += (&y4.x)[u] * wF[20736 + (i4 * 4 + u) * 8 + gf];
            }
            a += wF[21760 + gf];
            if (valid) {
                out[(size_t)bi * 16 + gf]     = __sinf(a);
                out[(size_t)bi * 16 + 8 + gf] = __cosf(a);
            }
        }
    }
}

// ---------------------------------------------------------------------------
extern "C" void kernel_launch(void* const* d_in, const int* in_sizes, int n_in,
                              void* d_out, int out_size, void* d_ws, size_t ws_size,
                              hipStream_t stream)
{
    const int*   indices = (const int*)  d_in[0];
    const float* states  = (const float*)d_in[1];
    const float* maps    = (const float*)d_in[2];
    const float* fc1_w   = (const float*)d_in[3];
    const float* fc1_b   = (const float*)d_in[4];
    const float* fc2_w   = (const float*)d_in[5];
    const float* fc2_b   = (const float*)d_in[6];
    const float* fc3_w   = (const float*)d_in[7];
    const float* fc3_b   = (const float*)d_in[8];
    const float* bn_w    = (const float*)d_in[9];
    const float* bn_b    = (const float*)d_in[10];
    const float* e_w     = (const float*)d_in[11];
    const float* e_b     = (const float*)d_in[12];
    const float* f_w     = (const float*)d_in[13];
    const float* f_b     = (const float*)d_in[14];
    float* out = (float*)d_out;

    float* ws   = (float*)d_ws;
    float* z    = ws;                    // 2048
    float* th_e = ws + 2048;             // 349184
    float* th_f = ws + 351232;           // 1393152
    int* counts  = (int*)(ws + 1744384); // 64
    int* offsets = counts + 64;          // 64
    int* perm    = counts + 128;         // 8192

    static int s_lds_optin = 0;
    if (!s_lds_optin) {
        hipFuncSetAttribute((const void*)func_kernel,
                            hipFuncAttributeMaxDynamicSharedMemorySize,
                            K3_LDS_BYTES);
        s_lds_optin = 1;
    }

    backbone_bucket_kernel<<<65, 1024, 0, stream>>>(
        maps, fc1_w, fc1_b, fc2_w, fc2_b, fc3_w, fc3_b, bn_w, bn_b, z,
        indices, counts, offsets, perm);
    theta_kernel<<<dim3(107, 8), 256, 0, stream>>>(
        z, e_w, e_b, f_w, f_b, th_e, th_f);
    func_kernel<<<dim3(NCLS, NSLICE), 512, K3_LDS_BYTES, stream>>>(
        states, th_e, th_f, counts, offsets, perm, out);
}

// Round 2
// 130.695 us; speedup vs baseline: 1.0865x; 1.0687x over previous
//
#include <hip/hip_runtime.h>
#include <hip/hip_bf16.h>

// ============================================================================
// indices ∈ [0,64) => backbone + theta have only 64 distinct rows. Compute
// per-class (7 MB, L2-resident), bucket batches by class, run only the tiny
// per-batch MLPs with class-shared weights.
// R6: 4 dispatches.
//  K0 = fc1 split over 256 blocks (class x col-quarter): 256KB/CU L2 traffic
//       instead of 1MB/CU (was ~8us L2-port-bound).
//  K1 = fc2+fc3+bn (64 blocks, reads h1 from ws) + bucket as block 64.
//  K2 = theta (unchanged).
//  K3 = func v6: 2 batches per thread (64 batches/pass) so every broadcast
//       weight-float4 feeds 16 FMAs (was 8) -> ~1.75x fewer LDS weight reads
//       per batch; NSLICE=3 -> typical 1 pass/block (no 2-pass tail).
//       W2f staged in two 32KB K-halves; dynamic LDS 145.5KB.
// ============================================================================

#define LEAKY 0.2f
#define NCLS 64
#define B_TOT 8192
#define NSLICE 3

// theta_e (per class, 5456 fl): W1e[0,128) b1e[128,192) W2e[192,4288)
//   b2e[4288,4352) W3e[4352,5376) b3e[5376,5392)
// theta_f (per class, 21768 fl): W1f[0,4096) b1f[4096,4224) W2f[4224,20608)
//   b2f[20608,20736) W3f[20736,21760) b3f[21760,21768)

__device__ __forceinline__ float lrelu(float x) { return x >= 0.f ? x : LEAKY * x; }

// ---------------------------------------------------------------------------
// K0: fc1 1024->256 split over 256 blocks: block = (class c = bx>>2, quarter
// q = bx&3). 1024 thr: o = q*64 + (t&63), 16 K-slices of 64. Per-block
// fc1_w read = 256KB (vs 1MB when one block did a whole class).
// ---------------------------------------------------------------------------
__global__ __launch_bounds__(1024) void fc1_kernel(
    const float* __restrict__ maps, const float* __restrict__ fc1_w,
    const float* __restrict__ fc1_b, float* __restrict__ h1g)
{
    __shared__ float m[1024];
    __shared__ float red[1024];
    const int t = threadIdx.x;
    const int c = blockIdx.x >> 2;
    const int q = blockIdx.x & 3;

    m[t] = maps[(size_t)c * 1024 + t];
    __syncthreads();

    const int ol = t & 63, ks = t >> 6;
    const int o = q * 64 + ol;
    const float* wp = fc1_w + o;
    float acc = 0.f;
#pragma unroll 8
    for (int i = 0; i < 64; ++i) {
        const int k = ks * 64 + i;
        acc += m[k] * wp[(size_t)k * 256];
    }
    red[t] = acc;
    __syncthreads();
    if (t < 64) {
        float a = fc1_b[q * 64 + t];
#pragma unroll
        for (int r = 0; r < 16; ++r) a += red[r * 64 + t];
        h1g[c * 256 + q * 64 + t] = lrelu(a);
    }
}

// ---------------------------------------------------------------------------
// K1: blocks 0..63: fc2+fc3+bn for class c (h1 from ws). block 64: bucket.
// 1024 threads.
// ---------------------------------------------------------------------------
__global__ __launch_bounds__(1024) void backbone_bucket_kernel(
    const float* __restrict__ h1g,
    const float* __restrict__ fc2_w, const float* __restrict__ fc2_b,
    const float* __restrict__ fc3_w, const float* __restrict__ fc3_b,
    const float* __restrict__ bn_w,  const float* __restrict__ bn_b,
    float* __restrict__ z,
    const int* __restrict__ idx, int* __restrict__ counts,
    int* __restrict__ offsets, int* __restrict__ perm)
{
    __shared__ float red[1024];
    __shared__ float h1[256];
    __shared__ float h2[128];
    __shared__ float h3[128];
    __shared__ int cnt[16][64];
    __shared__ int wcur[16][64];

    const int t = threadIdx.x;

    if (blockIdx.x == 64) {
        // ---------------- bucket ----------------
        const int w = t >> 6;
        cnt[w][t & 63] = 0;
        __syncthreads();
        int my[8];
#pragma unroll
        for (int r = 0; r < 8; ++r) {
            my[r] = idx[r * 1024 + t];
            atomicAdd(&cnt[w][my[r]], 1);
        }
        __syncthreads();
        if (t < 64) {
            int run = 0;
#pragma unroll
            for (int w2 = 0; w2 < 16; ++w2) {
                const int v = cnt[w2][t];
                wcur[w2][t] = run;
                run += v;
            }
            counts[t] = run;
            int x = run;
            for (int d = 1; d < 64; d <<= 1) {
                const int y = __shfl_up(x, d, 64);
                if (t >= d) x += y;
            }
            const int basec = x - run;
            offsets[t] = basec;
#pragma unroll
            for (int w2 = 0; w2 < 16; ++w2) wcur[w2][t] += basec;
        }
        __syncthreads();
#pragma unroll
        for (int r = 0; r < 8; ++r) {
            const int p = atomicAdd(&wcur[w][my[r]], 1);
            perm[p] = r * 1024 + t;
        }
        return;
    }

    // ---------------- fc2/fc3/bn for class c ----------------
    const int c = blockIdx.x;
    if (t < 256) h1[t] = h1g[c * 256 + t];
    __syncthreads();

    // fc2: 256 -> 128 (leaky); o = t&127, 8 K-slices of 32
    {
        const int o = t & 127, ks = t >> 7;
        float acc = 0.f;
#pragma unroll
        for (int i = 0; i < 32; ++i) {
            const int k = ks * 32 + i;
            acc += h1[k] * fc2_w[k * 128 + o];
        }
        red[t] = acc;
    }
    __syncthreads();
    if (t < 128) {
        float a = fc2_b[t];
#pragma unroll
        for (int r = 0; r < 8; ++r) a += red[r * 128 + t];
        h2[t] = lrelu(a);
    }
    __syncthreads();
    // fc3: 128 -> 128 (leaky); 8 K-slices of 16
    {
        const int o = t & 127, ks = t >> 7;
        float acc = 0.f;
#pragma unroll
        for (int i = 0; i < 16; ++i) {
            const int k = ks * 16 + i;
            acc += h2[k] * fc3_w[k * 128 + o];
        }
        red[t] = acc;
    }
    __syncthreads();
    if (t < 128) {
        float a = fc3_b[t];
#pragma unroll
        for (int r = 0; r < 8; ++r) a += red[r * 128 + t];
        h3[t] = lrelu(a);
    }
    __syncthreads();
    // bn: 128 -> 32 (no act); o = t&31, 32 K-slices of 4
    {
        const int o = t & 31, ks = t >> 5;
        float acc = 0.f;
#pragma unroll
        for (int i = 0; i < 4; ++i) {
            const int k = ks * 4 + i;
            acc += h3[k] * bn_w[k * 32 + o];
        }
        red[t] = acc;
    }
    __syncthreads();
    if (t < 32) {
        float a = bn_b[t];
#pragma unroll
        for (int r = 0; r < 32; ++r) a += red[r * 32 + t];
        z[c * 32 + t] = a;
    }
}

// ---------------------------------------------------------------------------
// K2: theta, grid (107, 8): block owns 256 cols x 8 classes. Weights in regs.
// ---------------------------------------------------------------------------
__global__ __launch_bounds__(256) void theta_kernel(
    const float* __restrict__ z,
    const float* __restrict__ e_w, const float* __restrict__ e_b,
    const float* __restrict__ f_w, const float* __restrict__ f_b,
    float* __restrict__ th_e, float* __restrict__ th_f)
{
    __shared__ __align__(16) float zl[2048];
    const int t = threadIdx.x;
    ((float4*)zl)[t]       = ((const float4*)z)[t];
    ((float4*)zl)[t + 256] = ((const float4*)z)[t + 256];
    __syncthreads();

    int j = blockIdx.x * 256 + t;
    const int cbase = blockIdx.y * 8;
    const float* wbase;
    float* op;
    int stride;
    float bias;
    if (j < 5456) {
        wbase = e_w + j; bias = e_b[j]; op = th_e + j; stride = 5456;
    } else {
        const int jj = j - 5456;
        if (jj >= 21768) return;
        wbase = f_w + jj; bias = f_b[jj]; op = th_f + jj; stride = 21768;
    }
    float wk[32];
#pragma unroll
    for (int k = 0; k < 32; ++k) wk[k] = wbase[(size_t)k * stride];

#pragma unroll
    for (int cc = 0; cc < 8; cc += 4) {
        const int c0 = cbase + cc;
        float a0 = bias, a1 = bias, a2 = bias, a3 = bias;
#pragma unroll
        for (int k4 = 0; k4 < 8; ++k4) {
            const float4 z0 = *(const float4*)&zl[(c0 + 0) * 32 + k4 * 4];
            const float4 z1 = *(const float4*)&zl[(c0 + 1) * 32 + k4 * 4];
            const float4 z2 = *(const float4*)&zl[(c0 + 2) * 32 + k4 * 4];
            const float4 z3 = *(const float4*)&zl[(c0 + 3) * 32 + k4 * 4];
            const float w0 = wk[k4 * 4], w1 = wk[k4 * 4 + 1];
            const float w2 = wk[k4 * 4 + 2], w3 = wk[k4 * 4 + 3];
            a0 += z0.x * w0 + z0.y * w1 + z0.z * w2 + z0.w * w3;
            a1 += z1.x * w0 + z1.y * w1 + z1.z * w2 + z1.w * w3;
            a2 += z2.x * w0 + z2.y * w1 + z2.z * w2 + z2.w * w3;
            a3 += z3.x * w0 + z3.y * w1 + z3.z * w2 + z3.w * w3;
        }
        op[(size_t)(c0 + 0) * stride] = a0;
        op[(size_t)(c0 + 1) * stride] = a1;
        op[(size_t)(c0 + 2) * stride] = a2;
        op[(size_t)(c0 + 3) * stride] = a3;
    }
}

// ---------------------------------------------------------------------------
// K3: func v6. grid (64, 3), 512 thr (8 waves). 64 batches/pass; each thread
// owns TWO batches so every broadcast weight read feeds 16 FMAs.
// LDS (floats): wE[5392] | wFa[5384] | wH[8192] | actA[8704] | actB[8704]
//   = 36376 fl = 145504 B (dynamic, opt-in). wFa = W1f+b1f | b2f+W3f+b3f.
//   wH = current 64-K-row half of W2f, staged twice per pass.
//   e: v = t&63 (batch), lo=S hi=G; ge = t>>6 (8 groups x 8 cols)
//   f: b = t&31 (+32), gf = t>>5 (16 groups x 8 cols)
// ---------------------------------------------------------------------------
#define ESTRIDE 68   // 17 float4s, odd -> conflict-free b128 across vbatches
#define FSTRIDE 132  // 33 float4s, odd

#define K3_LDS_FLOATS 36376
#define K3_LDS_BYTES  (K3_LDS_FLOATS * 4)

__global__ __launch_bounds__(512) void func_kernel(
    const float* __restrict__ states,
    const float* __restrict__ th_e_all, const float* __restrict__ th_f_all,
    const int* __restrict__ counts, const int* __restrict__ offsets,
    const int* __restrict__ perm, float* __restrict__ out)
{
    extern __shared__ float smem[];
    float* wE   = smem;             // 5392
    float* wFa  = smem + 5392;      // 5384
    float* wH   = smem + 10776;     // 8192
    float* actA = smem + 18968;     // 8704
    float* actB = smem + 27672;     // 8704

    const int c = blockIdx.x;
    const int s = blockIdx.y;
    const int nb   = counts[c];
    const int base = offsets[c];
    const int nblk = (nb + 63) >> 6;                       // 64-batch blocks
    const int npass = (nblk > s) ? ((nblk - 1 - s) / NSLICE + 1) : 0;
    if (npass == 0) return;

    const float* te = th_e_all + (size_t)c * 5456;
    const float* tf = th_f_all + (size_t)c * 21768;

    const int t  = threadIdx.x;
    const int b  = t & 31;
    const int v  = t & 63;
    const int ge = t >> 6;           // e col group (wave-uniform)
    const int gf = t >> 5;           // f col group (2 per wave)
    const int cole = ge * 8;
    const int colf = gf * 8;
    const int eoffL = v * ESTRIDE;
    const int eoffH = (v + 64) * ESTRIDE;
    const int foff0 = b * FSTRIDE;
    const int foff1 = (b + 32) * FSTRIDE;

    // ---- stage persistent weights once ----
    for (int j = t * 4; j < 5392; j += 2048)
        *(float4*)&wE[j] = *(const float4*)&te[j];
    for (int j = t * 4; j < 4224; j += 2048)
        *(float4*)&wFa[j] = *(const float4*)&tf[j];
    for (int j = t * 4; j < 1160; j += 2048)
        *(float4*)&wFa[4224 + j] = *(const float4*)&tf[20608 + j];

    for (int p = 0; p < npass; ++p) {
        __syncthreads();   // B1: staging visible / prev-pass reads done

        // stage W2f half 0 (k rows 0..63) — consumed after B5
        for (int j = t * 4; j < 8192; j += 2048)
            *(float4*)&wH[j] = *(const float4*)&tf[4224 + j];

        const int kbase = (p * NSLICE + s) << 6;
        const int ib_e  = kbase + v;
        const int bi_e  = (ib_e < nb) ? perm[base + ib_e] : 0;
        const float4 st = *(const float4*)&states[(size_t)bi_e * 4];

        // ---- e-L1: 2 -> 64 (leaky), both S (lo) and G (hi) ----
        {
            const float4 wa0 = *(const float4*)&wE[cole];
            const float4 wa1 = *(const float4*)&wE[cole + 4];
            const float4 wb0 = *(const float4*)&wE[64 + cole];
            const float4 wb1 = *(const float4*)&wE[64 + cole + 4];
            const float4 bb0 = *(const float4*)&wE[128 + cole];
            const float4 bb1 = *(const float4*)&wE[128 + cole + 4];
            float4 o0, o1;
            o0.x = lrelu(st.x * wa0.x + st.y * wb0.x + bb0.x);
            o0.y = lrelu(st.x * wa0.y + st.y * wb0.y + bb0.y);
            o0.z = lrelu(st.x * wa0.z + st.y * wb0.z + bb0.z);
            o0.w = lrelu(st.x * wa0.w + st.y * wb0.w + bb0.w);
            o1.x = lrelu(st.x * wa1.x + st.y * wb1.x + bb1.x);
            o1.y = lrelu(st.x * wa1.y + st.y * wb1.y + bb1.y);
            o1.z = lrelu(st.x * wa1.z + st.y * wb1.z + bb1.z);
            o1.w = lrelu(st.x * wa1.w + st.y * wb1.w + bb1.w);
            *(float4*)&actA[eoffL + cole]     = o0;
            *(float4*)&actA[eoffL + cole + 4] = o1;
            o0.x = lrelu(st.z * wa0.x + st.w * wb0.x + bb0.x);
            o0.y = lrelu(st.z * wa0.y + st.w * wb0.y + bb0.y);
            o0.z = lrelu(st.z * wa0.z + st.w * wb0.z + bb0.z);
            o0.w = lrelu(st.z * wa0.w + st.w * wb0.w + bb0.w);
            o1.x = lrelu(st.z * wa1.x + st.w * wb1.x + bb1.x);
            o1.y = lrelu(st.z * wa1.y + st.w * wb1.y + bb1.y);
            o1.z = lrelu(st.z * wa1.z + st.w * wb1.z + bb1.z);
            o1.w = lrelu(st.z * wa1.w + st.w * wb1.w + bb1.w);
            *(float4*)&actA[eoffH + cole]     = o0;
            *(float4*)&actA[eoffH + cole + 4] = o1;
        }
        __syncthreads();   // B2

        // ---- e-L2: 64 -> 64 (leaky), 2 vbatches/thread ----
        {
            float aL[8] = {0,0,0,0,0,0,0,0};
            float aH[8] = {0,0,0,0,0,0,0,0};
#pragma unroll 4
            for (int i4 = 0; i4 < 16; ++i4) {
                const float4 yL = *(const float4*)&actA[eoffL + i4 * 4];
                const float4 yH = *(const float4*)&actA[eoffH + i4 * 4];
#pragma unroll
                for (int u = 0; u < 4; ++u) {
                    const int row = 192 + (i4 * 4 + u) * 64 + cole;
                    const float4 wA = *(const float4*)&wE[row];
                    const float4 wB = *(const float4*)&wE[row + 4];
                    const float yl = (&yL.x)[u], yh = (&yH.x)[u];
                    aL[0] += yl * wA.x; aL[1] += yl * wA.y;
                    aL[2] += yl * wA.z; aL[3] += yl * wA.w;
                    aL[4] += yl * wB.x; aL[5] += yl * wB.y;
                    aL[6] += yl * wB.z; aL[7] += yl * wB.w;
                    aH[0] += yh * wA.x; aH[1] += yh * wA.y;
                    aH[2] += yh * wA.z; aH[3] += yh * wA.w;
                    aH[4] += yh * wB.x; aH[5] += yh * wB.y;
                    aH[6] += yh * wB.z; aH[7] += yh * wB.w;
                }
            }
            const float4 bA = *(const float4*)&wE[4288 + cole];
            const float4 bB = *(const float4*)&wE[4288 + cole + 4];
            float4 o0, o1;
            o0.x = lrelu(aL[0] + bA.x); o0.y = lrelu(aL[1] + bA.y);
            o0.z = lrelu(aL[2] + bA.z); o0.w = lrelu(aL[3] + bA.w);
            o1.x = lrelu(aL[4] + bB.x); o1.y = lrelu(aL[5] + bB.y);
            o1.z = lrelu(aL[6] + bB.z); o1.w = lrelu(aL[7] + bB.w);
            *(float4*)&actB[eoffL + cole]     = o0;
            *(float4*)&actB[eoffL + cole + 4] = o1;
            o0.x = lrelu(aH[0] + bA.x); o0.y = lrelu(aH[1] + bA.y);
            o0.z = lrelu(aH[2] + bA.z); o0.w = lrelu(aH[3] + bA.w);
            o1.x = lrelu(aH[4] + bB.x); o1.y = lrelu(aH[5] + bB.y);
            o1.z = lrelu(aH[6] + bB.z); o1.w = lrelu(aH[7] + bB.w);
            *(float4*)&actB[eoffH + cole]     = o0;
            *(float4*)&actB[eoffH + cole + 4] = o1;
        }
        __syncthreads();   // B3

        // ---- e-L3: 64 -> 16 (no act) -> zf (f-view of actA) ----
        {
            const int col3 = ge * 2;
            float a0 = 0.f, a1 = 0.f, a2 = 0.f, a3 = 0.f;
#pragma unroll 4
            for (int i4 = 0; i4 < 16; ++i4) {
                const float4 yL = *(const float4*)&actB[eoffL + i4 * 4];
                const float4 yH = *(const float4*)&actB[eoffH + i4 * 4];
#pragma unroll
                for (int u = 0; u < 4; ++u) {
                    const float2 w2 = *(const float2*)&wE[4352 + (i4 * 4 + u) * 16 + col3];
                    const float yl = (&yL.x)[u], yh = (&yH.x)[u];
                    a0 += yl * w2.x; a1 += yl * w2.y;
                    a2 += yh * w2.x; a3 += yh * w2.y;
                }
            }
            const float b0 = wE[5376 + col3], b1 = wE[5376 + col3 + 1];
            // lo = S -> zf[0..16), hi = G -> zf[16..32)
            actA[v * FSTRIDE + col3]          = a0 + b0;
            actA[v * FSTRIDE + col3 + 1]      = a1 + b1;
            actA[v * FSTRIDE + 16 + col3]     = a2 + b0;
            actA[v * FSTRIDE + 16 + col3 + 1] = a3 + b1;
        }
        __syncthreads();   // B4

        // ---- f-L1: 32 -> 128 (leaky), 2 batches/thread ----
        {
            float a0[8] = {0,0,0,0,0,0,0,0};
            float a1[8] = {0,0,0,0,0,0,0,0};
#pragma unroll
            for (int i4 = 0; i4 < 8; ++i4) {
                const float4 y0 = *(const float4*)&actA[foff0 + i4 * 4];
                const float4 y1 = *(const float4*)&actA[foff1 + i4 * 4];
#pragma unroll
                for (int u = 0; u < 4; ++u) {
                    const int row = (i4 * 4 + u) * 128 + colf;
                    const float4 wA = *(const float4*)&wFa[row];
                    const float4 wB = *(const float4*)&wFa[row + 4];
                    const float ya = (&y0.x)[u], yb = (&y1.x)[u];
                    a0[0] += ya * wA.x; a0[1] += ya * wA.y;
                    a0[2] += ya * wA.z; a0[3] += ya * wA.w;
                    a0[4] += ya * wB.x; a0[5] += ya * wB.y;
                    a0[6] += ya * wB.z; a0[7] += ya * wB.w;
                    a1[0] += yb * wA.x; a1[1] += yb * wA.y;
                    a1[2] += yb * wA.z; a1[3] += yb * wA.w;
                    a1[4] += yb * wB.x; a1[5] += yb * wB.y;
                    a1[6] += yb * wB.z; a1[7] += yb * wB.w;
                }
            }
            const float4 bA = *(const float4*)&wFa[4096 + colf];
            const float4 bB = *(const float4*)&wFa[4096 + colf + 4];
            float4 o0, o1;
            o0.x = lrelu(a0[0] + bA.x); o0.y = lrelu(a0[1] + bA.y);
            o0.z = lrelu(a0[2] + bA.z); o0.w = lrelu(a0[3] + bA.w);
            o1.x = lrelu(a0[4] + bB.x); o1.y = lrelu(a0[5] + bB.y);
            o1.z = lrelu(a0[6] + bB.z); o1.w = lrelu(a0[7] + bB.w);
            *(float4*)&actB[foff0 + colf]     = o0;
            *(float4*)&actB[foff0 + colf + 4] = o1;
            o0.x = lrelu(a1[0] + bA.x); o0.y = lrelu(a1[1] + bA.y);
            o0.z = lrelu(a1[2] + bA.z); o0.w = lrelu(a1[3] + bA.w);
            o1.x = lrelu(a1[4] + bB.x); o1.y = lrelu(a1[5] + bB.y);
            o1.z = lrelu(a1[6] + bB.z); o1.w = lrelu(a1[7] + bB.w);
            *(float4*)&actB[foff1 + colf]     = o0;
            *(float4*)&actB[foff1 + colf + 4] = o1;
        }
        __syncthreads();   // B5

        // ---- f-L2: 128 -> 128 (leaky), W2f in 2 staged K-halves ----
        {
            float a0[8] = {0,0,0,0,0,0,0,0};
            float a1[8] = {0,0,0,0,0,0,0,0};
            // half 0 (k 0..63) — wH staged at pass top
#pragma unroll 4
            for (int i4 = 0; i4 < 16; ++i4) {
                const float4 y0 = *(const float4*)&actB[foff0 + i4 * 4];
                const float4 y1 = *(const float4*)&actB[foff1 + i4 * 4];
#pragma unroll
                for (int u = 0; u < 4; ++u) {
                    const int row = (i4 * 4 + u) * 128 + colf;
                    const float4 wA = *(const float4*)&wH[row];
                    const float4 wB = *(const float4*)&wH[row + 4];
                    const float ya = (&y0.x)[u], yb = (&y1.x)[u];
                    a0[0] += ya * wA.x; a0[1] += ya * wA.y;
                    a0[2] += ya * wA.z; a0[3] += ya * wA.w;
                    a0[4] += ya * wB.x; a0[5] += ya * wB.y;
                    a0[6] += ya * wB.z; a0[7] += ya * wB.w;
                    a1[0] += yb * wA.x; a1[1] += yb * wA.y;
                    a1[2] += yb * wA.z; a1[3] += yb * wA.w;
                    a1[4] += yb * wB.x; a1[5] += yb * wB.y;
                    a1[6] += yb * wB.z; a1[7] += yb * wB.w;
                }
            }
            __syncthreads();   // B6: wH half-0 reads done
            for (int j = t * 4; j < 8192; j += 2048)
                *(float4*)&wH[j] = *(const float4*)&tf[4224 + 8192 + j];
            __syncthreads();   // B7: half 1 visible
#pragma unroll 4
            for (int i4 = 0; i4 < 16; ++i4) {
                const float4 y0 = *(const float4*)&actB[foff0 + 64 + i4 * 4];
                const float4 y1 = *(const float4*)&actB[foff1 + 64 + i4 * 4];
#pragma unroll
                for (int u = 0; u < 4; ++u) {
                    const int row = (i4 * 4 + u) * 128 + colf;
                    const float4 wA = *(const float4*)&wH[row];
                    const float4 wB = *(const float4*)&wH[row + 4];
                    const float ya = (&y0.x)[u], yb = (&y1.x)[u];
                    a0[0] += ya * wA.x; a0[1] += ya * wA.y;
                    a0[2] += ya * wA.z; a0[3] += ya * wA.w;
                    a0[4] += ya * wB.x; a0[5] += ya * wB.y;
                    a0[6] += ya * wB.z; a0[7] += ya * wB.w;
                    a1[0] += yb * wA.x; a1[1] += yb * wA.y;
                    a1[2] += yb * wA.z; a1[3] += yb * wA.w;
                    a1[4] += yb * wB.x; a1[5] += yb * wB.y;
                    a1[6] += yb * wB.z; a1[7] += yb * wB.w;
                }
            }
            const float4 bA = *(const float4*)&wFa[4224 + colf];
            const float4 bB = *(const float4*)&wFa[4224 + colf + 4];
            float4 o0, o1;
            o0.x = lrelu(a0[0] + bA.x); o0.y = lrelu(a0[1] + bA.y);
            o0.z = lrelu(a0[2] + bA.z); o0.w = lrelu(a0[3] + bA.w);
            o1.x = lrelu(a0[4] + bB.x); o1.y = lrelu(a0[5] + bB.y);
            o1.z = lrelu(a0[6] + bB.z); o1.w = lrelu(a0[7] + bB.w);
            *(float4*)&actA[foff0 + colf]     = o0;
            *(float4*)&actA[foff0 + colf + 4] = o1;
            o0.x = lrelu(a1[0] + bA.x); o0.y = lrelu(a1[1] + bA.y);
            o0.z = lrelu(a1[2] + bA.z); o0.w = lrelu(a1[3] + bA.w);
            o1.x = lrelu(a1[4] + bB.x); o1.y = lrelu(a1[5] + bB.y);
            o1.z = lrelu(a1[6] + bB.z); o1.w = lrelu(a1[7] + bB.w);
            *(float4*)&actA[foff1 + colf]     = o0;
            *(float4*)&actA[foff1 + colf + 4] = o1;
        }
        __syncthreads();   // B8

        // ---- f-L3: 128 -> 8 (no act) + sin/cos, 2 batches/thread ----
        if (gf < 8) {
            float a0 = 0.f, a1 = 0.f;
#pragma unroll 8
            for (int i4 = 0; i4 < 32; ++i4) {
                const float4 y0 = *(const float4*)&actA[foff0 + i4 * 4];
                const float4 y1 = *(const float4*)&actA[foff1 + i4 * 4];
#pragma unroll
                for (int u = 0; u < 4; ++u) {
                    const float w = wFa[4352 + (i4 * 4 + u) * 8 + gf];
                    a0 += (&y0.x)[u] * w;
                    a1 += (&y1.x)[u] * w;
                }
            }
            const float bb = wFa[5376 + gf];
            a0 += bb; a1 += bb;
            const int ib0 = kbase + b, ib1 = kbase + b + 32;
            if (ib0 < nb) {
                const int bi = perm[base + ib0];
                out[(size_t)bi * 16 + gf]     = __sinf(a0);
                out[(size_t)bi * 16 + 8 + gf] = __cosf(a0);
            }
            if (ib1 < nb) {
                const int bi = perm[base + ib1];
                out[(size_t)bi * 16 + gf]     = __sinf(a1);
                out[(size_t)bi * 16 + 8 + gf] = __cosf(a1);
            }
        }
    }
}

// ---------------------------------------------------------------------------
extern "C" void kernel_launch(void* const* d_in, const int* in_sizes, int n_in,
                              void* d_out, int out_size, void* d_ws, size_t ws_size,
                              hipStream_t stream)
{
    const int*   indices = (const int*)  d_in[0];
    const float* states  = (const float*)d_in[1];
    const float* maps    = (const float*)d_in[2];
    const float* fc1_w   = (const float*)d_in[3];
    const float* fc1_b   = (const float*)d_in[4];
    const float* fc2_w   = (const float*)d_in[5];
    const float* fc2_b   = (const float*)d_in[6];
    const float* fc3_w   = (const float*)d_in[7];
    const float* fc3_b   = (const float*)d_in[8];
    const float* bn_w    = (const float*)d_in[9];
    const float* bn_b    = (const float*)d_in[10];
    const float* e_w     = (const float*)d_in[11];
    const float* e_b     = (const float*)d_in[12];
    const float* f_w     = (const float*)d_in[13];
    const float* f_b     = (const float*)d_in[14];
    float* out = (float*)d_out;

    float* ws   = (float*)d_ws;
    float* z    = ws;                    // 2048
    float* th_e = ws + 2048;             // 349184
    float* th_f = ws + 351232;           // 1393152
    int* counts  = (int*)(ws + 1744384); // 64
    int* offsets = counts + 64;          // 64
    int* perm    = counts + 128;         // 8192
    float* h1g   = ws + 1752704;         // 16384

    static int s_lds_optin = 0;
    if (!s_lds_optin) {
        hipFuncSetAttribute((const void*)func_kernel,
                            hipFuncAttributeMaxDynamicSharedMemorySize,
                            K3_LDS_BYTES);
        s_lds_optin = 1;
    }

    fc1_kernel<<<256, 1024, 0, stream>>>(maps, fc1_w, fc1_b, h1g);
    backbone_bucket_kernel<<<65, 1024, 0, stream>>>(
        h1g, fc2_w, fc2_b, fc3_w, fc3_b, bn_w, bn_b, z,
        indices, counts, offsets, perm);
    theta_kernel<<<dim3(107, 8), 256, 0, stream>>>(
        z, e_w, e_b, f_w, f_b, th_e, th_f);
    func_kernel<<<dim3(NCLS, NSLICE), 512, K3_LDS_BYTES, stream>>>(
        states, th_e, th_f, counts, offsets, perm, out);
}

// Round 3
// 130.463 us; speedup vs baseline: 1.0884x; 1.0018x over previous
//
#include <hip/hip_runtime.h>
#include <hip/hip_bf16.h>

// ============================================================================
// indices ∈ [0,64) => backbone + theta have only 64 distinct rows. Compute
// per-class (7 MB, L2-resident), bucket batches by class, run only the tiny
// per-batch MLPs with class-shared weights.
// R7: K3 v7 — batch-balanced grid (64,4) = 256 blocks (all CUs), ONE pass of
// capacity 48 per block (3 batches/thread: subs +16/+32 f, +32/+64 e).
// 24 FMAs per broadcast weight float4; 4-6 active waves/phase (>=1/SIMD).
// Bank-aware index order: e col-group in low bits (eg=t&7), f batch in low
// bits (bp=t&15) -> weight reads conflict-free, act reads <=2-way.
// LDS 128.1KB. K0/K1/K2 unchanged from R6.
// ============================================================================

#define LEAKY 0.2f
#define NCLS 64
#define B_TOT 8192
#define CAP 48            // batches per K3 pass (capacity)

// theta_e (per class, 5456 fl): W1e[0,128) b1e[128,192) W2e[192,4288)
//   b2e[4288,4352) W3e[4352,5376) b3e[5376,5392)
// theta_f (per class, 21768 fl): W1f[0,4096) b1f[4096,4224) W2f[4224,20608)
//   b2f[20608,20736) W3f[20736,21760) b3f[21760,21768)

__device__ __forceinline__ float lrelu(float x) { return x >= 0.f ? x : LEAKY * x; }

// ---------------------------------------------------------------------------
// K0: fc1 1024->256 split over 256 blocks: block = (class c = bx>>2, quarter
// q = bx&3). 1024 thr: o = q*64 + (t&63), 16 K-slices of 64.
// ---------------------------------------------------------------------------
__global__ __launch_bounds__(1024) void fc1_kernel(
    const float* __restrict__ maps, const float* __restrict__ fc1_w,
    const float* __restrict__ fc1_b, float* __restrict__ h1g)
{
    __shared__ float m[1024];
    __shared__ float red[1024];
    const int t = threadIdx.x;
    const int c = blockIdx.x >> 2;
    const int q = blockIdx.x & 3;

    m[t] = maps[(size_t)c * 1024 + t];
    __syncthreads();

    const int ol = t & 63, ks = t >> 6;
    const int o = q * 64 + ol;
    const float* wp = fc1_w + o;
    float acc = 0.f;
#pragma unroll 8
    for (int i = 0; i < 64; ++i) {
        const int k = ks * 64 + i;
        acc += m[k] * wp[(size_t)k * 256];
    }
    red[t] = acc;
    __syncthreads();
    if (t < 64) {
        float a = fc1_b[q * 64 + t];
#pragma unroll
        for (int r = 0; r < 16; ++r) a += red[r * 64 + t];
        h1g[c * 256 + q * 64 + t] = lrelu(a);
    }
}

// ---------------------------------------------------------------------------
// K1: blocks 0..63: fc2+fc3+bn for class c (h1 from ws). block 64: bucket.
// ---------------------------------------------------------------------------
__global__ __launch_bounds__(1024) void backbone_bucket_kernel(
    const float* __restrict__ h1g,
    const float* __restrict__ fc2_w, const float* __restrict__ fc2_b,
    const float* __restrict__ fc3_w, const float* __restrict__ fc3_b,
    const float* __restrict__ bn_w,  const float* __restrict__ bn_b,
    float* __restrict__ z,
    const int* __restrict__ idx, int* __restrict__ counts,
    int* __restrict__ offsets, int* __restrict__ perm)
{
    __shared__ float red[1024];
    __shared__ float h1[256];
    __shared__ float h2[128];
    __shared__ float h3[128];
    __shared__ int cnt[16][64];
    __shared__ int wcur[16][64];

    const int t = threadIdx.x;

    if (blockIdx.x == 64) {
        // ---------------- bucket ----------------
        const int w = t >> 6;
        cnt[w][t & 63] = 0;
        __syncthreads();
        int my[8];
#pragma unroll
        for (int r = 0; r < 8; ++r) {
            my[r] = idx[r * 1024 + t];
            atomicAdd(&cnt[w][my[r]], 1);
        }
        __syncthreads();
        if (t < 64) {
            int run = 0;
#pragma unroll
            for (int w2 = 0; w2 < 16; ++w2) {
                const int v = cnt[w2][t];
                wcur[w2][t] = run;
                run += v;
            }
            counts[t] = run;
            int x = run;
            for (int d = 1; d < 64; d <<= 1) {
                const int y = __shfl_up(x, d, 64);
                if (t >= d) x += y;
            }
            const int basec = x - run;
            offsets[t] = basec;
#pragma unroll
            for (int w2 = 0; w2 < 16; ++w2) wcur[w2][t] += basec;
        }
        __syncthreads();
#pragma unroll
        for (int r = 0; r < 8; ++r) {
            const int p = atomicAdd(&wcur[w][my[r]], 1);
            perm[p] = r * 1024 + t;
        }
        return;
    }

    // ---------------- fc2/fc3/bn for class c ----------------
    const int c = blockIdx.x;
    if (t < 256) h1[t] = h1g[c * 256 + t];
    __syncthreads();

    // fc2: 256 -> 128 (leaky)
    {
        const int o = t & 127, ks = t >> 7;
        float acc = 0.f;
#pragma unroll
        for (int i = 0; i < 32; ++i) {
            const int k = ks * 32 + i;
            acc += h1[k] * fc2_w[k * 128 + o];
        }
        red[t] = acc;
    }
    __syncthreads();
    if (t < 128) {
        float a = fc2_b[t];
#pragma unroll
        for (int r = 0; r < 8; ++r) a += red[r * 128 + t];
        h2[t] = lrelu(a);
    }
    __syncthreads();
    // fc3: 128 -> 128 (leaky)
    {
        const int o = t & 127, ks = t >> 7;
        float acc = 0.f;
#pragma unroll
        for (int i = 0; i < 16; ++i) {
            const int k = ks * 16 + i;
            acc += h2[k] * fc3_w[k * 128 + o];
        }
        red[t] = acc;
    }
    __syncthreads();
    if (t < 128) {
        float a = fc3_b[t];
#pragma unroll
        for (int r = 0; r < 8; ++r) a += red[r * 128 + t];
        h3[t] = lrelu(a);
    }
    __syncthreads();
    // bn: 128 -> 32 (no act)
    {
        const int o = t & 31, ks = t >> 5;
        float acc = 0.f;
#pragma unroll
        for (int i = 0; i < 4; ++i) {
            const int k = ks * 4 + i;
            acc += h3[k] * bn_w[k * 32 + o];
        }
        red[t] = acc;
    }
    __syncthreads();
    if (t < 32) {
        float a = bn_b[t];
#pragma unroll
        for (int r = 0; r < 32; ++r) a += red[r * 32 + t];
        z[c * 32 + t] = a;
    }
}

// ---------------------------------------------------------------------------
// K2: theta, grid (107, 8): block owns 256 cols x 8 classes. Weights in regs.
// ---------------------------------------------------------------------------
__global__ __launch_bounds__(256) void theta_kernel(
    const float* __restrict__ z,
    const float* __restrict__ e_w, const float* __restrict__ e_b,
    const float* __restrict__ f_w, const float* __restrict__ f_b,
    float* __restrict__ th_e, float* __restrict__ th_f)
{
    __shared__ __align__(16) float zl[2048];
    const int t = threadIdx.x;
    ((float4*)zl)[t]       = ((const float4*)z)[t];
    ((float4*)zl)[t + 256] = ((const float4*)z)[t + 256];
    __syncthreads();

    int j = blockIdx.x * 256 + t;
    const int cbase = blockIdx.y * 8;
    const float* wbase;
    float* op;
    int stride;
    float bias;
    if (j < 5456) {
        wbase = e_w + j; bias = e_b[j]; op = th_e + j; stride = 5456;
    } else {
        const int jj = j - 5456;
        if (jj >= 21768) return;
        wbase = f_w + jj; bias = f_b[jj]; op = th_f + jj; stride = 21768;
    }
    float wk[32];
#pragma unroll
    for (int k = 0; k < 32; ++k) wk[k] = wbase[(size_t)k * stride];

#pragma unroll
    for (int cc = 0; cc < 8; cc += 4) {
        const int c0 = cbase + cc;
        float a0 = bias, a1 = bias, a2 = bias, a3 = bias;
#pragma unroll
        for (int k4 = 0; k4 < 8; ++k4) {
            const float4 z0 = *(const float4*)&zl[(c0 + 0) * 32 + k4 * 4];
            const float4 z1 = *(const float4*)&zl[(c0 + 1) * 32 + k4 * 4];
            const float4 z2 = *(const float4*)&zl[(c0 + 2) * 32 + k4 * 4];
            const float4 z3 = *(const float4*)&zl[(c0 + 3) * 32 + k4 * 4];
            const float w0 = wk[k4 * 4], w1 = wk[k4 * 4 + 1];
            const float w2 = wk[k4 * 4 + 2], w3 = wk[k4 * 4 + 3];
            a0 += z0.x * w0 + z0.y * w1 + z0.z * w2 + z0.w * w3;
            a1 += z1.x * w0 + z1.y * w1 + z1.z * w2 + z1.w * w3;
            a2 += z2.x * w0 + z2.y * w1 + z2.z * w2 + z2.w * w3;
            a3 += z3.x * w0 + z3.y * w1 + z3.z * w2 + z3.w * w3;
        }
        op[(size_t)(c0 + 0) * stride] = a0;
        op[(size_t)(c0 + 1) * stride] = a1;
        op[(size_t)(c0 + 2) * stride] = a2;
        op[(size_t)(c0 + 3) * stride] = a3;
    }
}

// ---------------------------------------------------------------------------
// K3: func v7. grid (64, 4), 512 thr. Slice s handles a balanced ~nb/4 chunk
// of its class, in ONE pass of capacity 48 (3 batches/thread).
// LDS (floats): wE[5392] | wFa[5384] | wH[8192] | actA[6528] | actB[6528]
//   = 32024 fl = 128096 B (dynamic). wFa = W1f+b1f | b2f | W3f | b3f.
//   wH = current 64-K-row half of W2f, staged twice per pass.
// e phases (t<256): eg = t&7 (8 col groups of 8), vp = t>>3; vb = vp+{0,32,64}
//   (vb = batch*2 + state). f phases (t<256): bp = t&15, fg = t>>4 (16 groups
//   of 8); fb = bp+{0,16,32}. f-L3 (t<384): col = t&7, fb3 = t>>3.
// ---------------------------------------------------------------------------
#define ESTRIDE 68   // 17 float4s, odd
#define FSTRIDE 132  // 33 float4s, odd

#define K3_LDS_FLOATS 32024
#define K3_LDS_BYTES  (K3_LDS_FLOATS * 4)

__global__ __launch_bounds__(512) void func_kernel(
    const float* __restrict__ states,
    const float* __restrict__ th_e_all, const float* __restrict__ th_f_all,
    const int* __restrict__ counts, const int* __restrict__ offsets,
    const int* __restrict__ perm, float* __restrict__ out)
{
    extern __shared__ float smem[];
    float* wE   = smem;             // 5392
    float* wFa  = smem + 5392;      // 5384
    float* wH   = smem + 10776;     // 8192
    float* actA = smem + 18968;     // 6528
    float* actB = smem + 25496;     // 6528

    const int c = blockIdx.x;
    const int s = blockIdx.y;
    const int nb   = counts[c];
    const int base = offsets[c];
    const int q = nb >> 2, r = nb & 3;
    const int lo  = s * q + (s < r ? s : r);
    const int cnt = q + (s < r ? 1 : 0);
    if (cnt == 0) return;
    const int hi = lo + cnt;

    const float* te = th_e_all + (size_t)c * 5456;
    const float* tf = th_f_all + (size_t)c * 21768;

    const int t  = threadIdx.x;
    const int eg = t & 7,  vp = t >> 3;    // e mapping (valid t<256)
    const int bp = t & 15, fg = t >> 4;    // f mapping (valid t<256)
    const int cole = eg * 8;
    const int colf = fg * 8;
    const int col8 = t & 7, fb3 = t >> 3;  // f-L3 mapping (valid t<384)

    // ---- stage persistent weights once ----
    for (int j = t * 4; j < 5392; j += 2048)
        *(float4*)&wE[j] = *(const float4*)&te[j];
    for (int j = t * 4; j < 4224; j += 2048)
        *(float4*)&wFa[j] = *(const float4*)&tf[j];
    for (int j = t * 4; j < 1160; j += 2048)
        *(float4*)&wFa[4224 + j] = *(const float4*)&tf[20608 + j];

    const int npass = (cnt + CAP - 1) / CAP;   // 1 in practice
    for (int p = 0; p < npass; ++p) {
        __syncthreads();   // B1: staging visible / prev-pass reads done

        // stage W2f half 0 (k rows 0..63) — consumed after B5
        for (int j = t * 4; j < 8192; j += 2048)
            *(float4*)&wH[j] = *(const float4*)&tf[4224 + j];

        const int pb = lo + p * CAP;   // first class-local batch this pass

        // ---- e-L1: 2 -> 64 (leaky), 3 vb/thread ----
        if (t < 256) {
            const float4 wa0 = *(const float4*)&wE[cole];
            const float4 wa1 = *(const float4*)&wE[cole + 4];
            const float4 wb0 = *(const float4*)&wE[64 + cole];
            const float4 wb1 = *(const float4*)&wE[64 + cole + 4];
            const float4 bb0 = *(const float4*)&wE[128 + cole];
            const float4 bb1 = *(const float4*)&wE[128 + cole + 4];
#pragma unroll
            for (int sub = 0; sub < 3; ++sub) {
                const int vb = vp + 32 * sub;
                const int fb = vb >> 1, ve = vb & 1;
                const int ib = pb + fb;
                const int bi = (ib < hi) ? perm[base + ib] : 0;
                const float2 sv = *(const float2*)&states[(size_t)bi * 4 + 2 * ve];
                float4 o0, o1;
                o0.x = lrelu(sv.x * wa0.x + sv.y * wb0.x + bb0.x);
                o0.y = lrelu(sv.x * wa0.y + sv.y * wb0.y + bb0.y);
                o0.z = lrelu(sv.x * wa0.z + sv.y * wb0.z + bb0.z);
                o0.w = lrelu(sv.x * wa0.w + sv.y * wb0.w + bb0.w);
                o1.x = lrelu(sv.x * wa1.x + sv.y * wb1.x + bb1.x);
                o1.y = lrelu(sv.x * wa1.y + sv.y * wb1.y + bb1.y);
                o1.z = lrelu(sv.x * wa1.z + sv.y * wb1.z + bb1.z);
                o1.w = lrelu(sv.x * wa1.w + sv.y * wb1.w + bb1.w);
                *(float4*)&actA[vb * ESTRIDE + cole]     = o0;
                *(float4*)&actA[vb * ESTRIDE + cole + 4] = o1;
            }
        }
        __syncthreads();   // B2

        // ---- e-L2: 64 -> 64 (leaky), 3 vb/thread ----
        if (t < 256) {
            const int e0 = vp * ESTRIDE;
            const int e1 = (vp + 32) * ESTRIDE;
            const int e2 = (vp + 64) * ESTRIDE;
            float a0[8] = {0,0,0,0,0,0,0,0};
            float a1[8] = {0,0,0,0,0,0,0,0};
            float a2[8] = {0,0,0,0,0,0,0,0};
#pragma unroll 4
            for (int i4 = 0; i4 < 16; ++i4) {
                const float4 y0 = *(const float4*)&actA[e0 + i4 * 4];
                const float4 y1 = *(const float4*)&actA[e1 + i4 * 4];
                const float4 y2 = *(const float4*)&actA[e2 + i4 * 4];
#pragma unroll
                for (int u = 0; u < 4; ++u) {
                    const int row = 192 + (i4 * 4 + u) * 64 + cole;
                    const float4 wA = *(const float4*)&wE[row];
                    const float4 wB = *(const float4*)&wE[row + 4];
                    const float v0 = (&y0.x)[u], v1 = (&y1.x)[u], v2 = (&y2.x)[u];
                    a0[0] += v0 * wA.x; a0[1] += v0 * wA.y;
                    a0[2] += v0 * wA.z; a0[3] += v0 * wA.w;
                    a0[4] += v0 * wB.x; a0[5] += v0 * wB.y;
                    a0[6] += v0 * wB.z; a0[7] += v0 * wB.w;
                    a1[0] += v1 * wA.x; a1[1] += v1 * wA.y;
                    a1[2] += v1 * wA.z; a1[3] += v1 * wA.w;
                    a1[4] += v1 * wB.x; a1[5] += v1 * wB.y;
                    a1[6] += v1 * wB.z; a1[7] += v1 * wB.w;
                    a2[0] += v2 * wA.x; a2[1] += v2 * wA.y;
                    a2[2] += v2 * wA.z; a2[3] += v2 * wA.w;
                    a2[4] += v2 * wB.x; a2[5] += v2 * wB.y;
                    a2[6] += v2 * wB.z; a2[7] += v2 * wB.w;
                }
            }
            const float4 bA = *(const float4*)&wE[4288 + cole];
            const float4 bB = *(const float4*)&wE[4288 + cole + 4];
            float4 o0, o1;
            o0.x = lrelu(a0[0] + bA.x); o0.y = lrelu(a0[1] + bA.y);
            o0.z = lrelu(a0[2] + bA.z); o0.w = lrelu(a0[3] + bA.w);
            o1.x = lrelu(a0[4] + bB.x); o1.y = lrelu(a0[5] + bB.y);
            o1.z = lrelu(a0[6] + bB.z); o1.w = lrelu(a0[7] + bB.w);
            *(float4*)&actB[e0 + cole]     = o0;
            *(float4*)&actB[e0 + cole + 4] = o1;
            o0.x = lrelu(a1[0] + bA.x); o0.y = lrelu(a1[1] + bA.y);
            o0.z = lrelu(a1[2] + bA.z); o0.w = lrelu(a1[3] + bA.w);
            o1.x = lrelu(a1[4] + bB.x); o1.y = lrelu(a1[5] + bB.y);
            o1.z = lrelu(a1[6] + bB.z); o1.w = lrelu(a1[7] + bB.w);
            *(float4*)&actB[e1 + cole]     = o0;
            *(float4*)&actB[e1 + cole + 4] = o1;
            o0.x = lrelu(a2[0] + bA.x); o0.y = lrelu(a2[1] + bA.y);
            o0.z = lrelu(a2[2] + bA.z); o0.w = lrelu(a2[3] + bA.w);
            o1.x = lrelu(a2[4] + bB.x); o1.y = lrelu(a2[5] + bB.y);
            o1.z = lrelu(a2[6] + bB.z); o1.w = lrelu(a2[7] + bB.w);
            *(float4*)&actB[e2 + cole]     = o0;
            *(float4*)&actB[e2 + cole + 4] = o1;
        }
        __syncthreads();   // B3

        // ---- e-L3: 64 -> 16 (no act) -> zf (f-layout in actA) ----
        if (t < 256) {
            const int col3 = eg * 2;
            const int e0 = vp * ESTRIDE;
            const int e1 = (vp + 32) * ESTRIDE;
            const int e2 = (vp + 64) * ESTRIDE;
            float a00 = 0.f, a01 = 0.f, a10 = 0.f, a11 = 0.f, a20 = 0.f, a21 = 0.f;
#pragma unroll 4
            for (int i4 = 0; i4 < 16; ++i4) {
                const float4 y0 = *(const float4*)&actB[e0 + i4 * 4];
                const float4 y1 = *(const float4*)&actB[e1 + i4 * 4];
                const float4 y2 = *(const float4*)&actB[e2 + i4 * 4];
#pragma unroll
                for (int u = 0; u < 4; ++u) {
                    const float2 w2 = *(const float2*)&wE[4352 + (i4 * 4 + u) * 16 + col3];
                    const float v0 = (&y0.x)[u], v1 = (&y1.x)[u], v2 = (&y2.x)[u];
                    a00 += v0 * w2.x; a01 += v0 * w2.y;
                    a10 += v1 * w2.x; a11 += v1 * w2.y;
                    a20 += v2 * w2.x; a21 += v2 * w2.y;
                }
            }
            const float b0 = wE[5376 + col3], b1 = wE[5376 + col3 + 1];
            {
                const int vb = vp, fb = vb >> 1, ve = vb & 1;
                actA[fb * FSTRIDE + ve * 16 + col3]     = a00 + b0;
                actA[fb * FSTRIDE + ve * 16 + col3 + 1] = a01 + b1;
            }
            {
                const int vb = vp + 32, fb = vb >> 1, ve = vb & 1;
                actA[fb * FSTRIDE + ve * 16 + col3]     = a10 + b0;
                actA[fb * FSTRIDE + ve * 16 + col3 + 1] = a11 + b1;
            }
            {
                const int vb = vp + 64, fb = vb >> 1, ve = vb & 1;
                actA[fb * FSTRIDE + ve * 16 + col3]     = a20 + b0;
                actA[fb * FSTRIDE + ve * 16 + col3 + 1] = a21 + b1;
            }
        }
        __syncthreads();   // B4

        // ---- f-L1: 32 -> 128 (leaky), 3 batches/thread ----
        if (t < 256) {
            const int f0 = bp * FSTRIDE;
            const int f1 = (bp + 16) * FSTRIDE;
            const int f2 = (bp + 32) * FSTRIDE;
            float a0[8] = {0,0,0,0,0,0,0,0};
            float a1[8] = {0,0,0,0,0,0,0,0};
            float a2[8] = {0,0,0,0,0,0,0,0};
#pragma unroll
            for (int i4 = 0; i4 < 8; ++i4) {
                const float4 y0 = *(const float4*)&actA[f0 + i4 * 4];
                const float4 y1 = *(const float4*)&actA[f1 + i4 * 4];
                const float4 y2 = *(const float4*)&actA[f2 + i4 * 4];
#pragma unroll
                for (int u = 0; u < 4; ++u) {
                    const int row = (i4 * 4 + u) * 128 + colf;
                    const float4 wA = *(const float4*)&wFa[row];
                    const float4 wB = *(const float4*)&wFa[row + 4];
                    const float v0 = (&y0.x)[u], v1 = (&y1.x)[u], v2 = (&y2.x)[u];
                    a0[0] += v0 * wA.x; a0[1] += v0 * wA.y;
                    a0[2] += v0 * wA.z; a0[3] += v0 * wA.w;
                    a0[4] += v0 * wB.x; a0[5] += v0 * wB.y;
                    a0[6] += v0 * wB.z; a0[7] += v0 * wB.w;
                    a1[0] += v1 * wA.x; a1[1] += v1 * wA.y;
                    a1[2] += v1 * wA.z; a1[3] += v1 * wA.w;
                    a1[4] += v1 * wB.x; a1[5] += v1 * wB.y;
                    a1[6] += v1 * wB.z; a1[7] += v1 * wB.w;
                    a2[0] += v2 * wA.x; a2[1] += v2 * wA.y;
                    a2[2] += v2 * wA.z; a2[3] += v2 * wA.w;
                    a2[4] += v2 * wB.x; a2[5] += v2 * wB.y;
                    a2[6] += v2 * wB.z; a2[7] += v2 * wB.w;
                }
            }
            const float4 bA = *(const float4*)&wFa[4096 + colf];
            const float4 bB = *(const float4*)&wFa[4096 + colf + 4];
            float4 o0, o1;
            o0.x = lrelu(a0[0] + bA.x); o0.y = lrelu(a0[1] + bA.y);
            o0.z = lrelu(a0[2] + bA.z); o0.w = lrelu(a0[3] + bA.w);
            o1.x = lrelu(a0[4] + bB.x); o1.y = lrelu(a0[5] + bB.y);
            o1.z = lrelu(a0[6] + bB.z); o1.w = lrelu(a0[7] + bB.w);
            *(float4*)&actB[f0 + colf]     = o0;
            *(float4*)&actB[f0 + colf + 4] = o1;
            o0.x = lrelu(a1[0] + bA.x); o0.y = lrelu(a1[1] + bA.y);
            o0.z = lrelu(a1[2] + bA.z); o0.w = lrelu(a1[3] + bA.w);
            o1.x = lrelu(a1[4] + bB.x); o1.y = lrelu(a1[5] + bB.y);
            o1.z = lrelu(a1[6] + bB.z); o1.w = lrelu(a1[7] + bB.w);
            *(float4*)&actB[f1 + colf]     = o0;
            *(float4*)&actB[f1 + colf + 4] = o1;
            o0.x = lrelu(a2[0] + bA.x); o0.y = lrelu(a2[1] + bA.y);
            o0.z = lrelu(a2[2] + bA.z); o0.w = lrelu(a2[3] + bA.w);
            o1.x = lrelu(a2[4] + bB.x); o1.y = lrelu(a2[5] + bB.y);
            o1.z = lrelu(a2[6] + bB.z); o1.w = lrelu(a2[7] + bB.w);
            *(float4*)&actB[f2 + colf]     = o0;
            *(float4*)&actB[f2 + colf + 4] = o1;
        }
        __syncthreads();   // B5

        // ---- f-L2: 128 -> 128 (leaky), W2f in 2 staged K-halves ----
        {
            const int f0 = bp * FSTRIDE;
            const int f1 = (bp + 16) * FSTRIDE;
            const int f2 = (bp + 32) * FSTRIDE;
            float a0[8] = {0,0,0,0,0,0,0,0};
            float a1[8] = {0,0,0,0,0,0,0,0};
            float a2[8] = {0,0,0,0,0,0,0,0};
            if (t < 256) {
#pragma unroll 4
                for (int i4 = 0; i4 < 16; ++i4) {
                    const float4 y0 = *(const float4*)&actB[f0 + i4 * 4];
                    const float4 y1 = *(const float4*)&actB[f1 + i4 * 4];
                    const float4 y2 = *(const float4*)&actB[f2 + i4 * 4];
#pragma unroll
                    for (int u = 0; u < 4; ++u) {
                        const int row = (i4 * 4 + u) * 128 + colf;
                        const float4 wA = *(const float4*)&wH[row];
                        const float4 wB = *(const float4*)&wH[row + 4];
                        const float v0 = (&y0.x)[u], v1 = (&y1.x)[u], v2 = (&y2.x)[u];
                        a0[0] += v0 * wA.x; a0[1] += v0 * wA.y;
                        a0[2] += v0 * wA.z; a0[3] += v0 * wA.w;
                        a0[4] += v0 * wB.x; a0[5] += v0 * wB.y;
                        a0[6] += v0 * wB.z; a0[7] += v0 * wB.w;
                        a1[0] += v1 * wA.x; a1[1] += v1 * wA.y;
                        a1[2] += v1 * wA.z; a1[3] += v1 * wA.w;
                        a1[4] += v1 * wB.x; a1[5] += v1 * wB.y;
                        a1[6] += v1 * wB.z; a1[7] += v1 * wB.w;
                        a2[0] += v2 * wA.x; a2[1] += v2 * wA.y;
                        a2[2] += v2 * wA.z; a2[3] += v2 * wA.w;
                        a2[4] += v2 * wB.x; a2[5] += v2 * wB.y;
                        a2[6] += v2 * wB.z; a2[7] += v2 * wB.w;
                    }
                }
            }
            __syncthreads();   // B6: wH half-0 reads done
            for (int j = t * 4; j < 8192; j += 2048)
                *(float4*)&wH[j] = *(const float4*)&tf[4224 + 8192 + j];
            __syncthreads();   // B7: half 1 visible
            if (t < 256) {
#pragma unroll 4
                for (int i4 = 0; i4 < 16; ++i4) {
                    const float4 y0 = *(const float4*)&actB[f0 + 64 + i4 * 4];
                    const float4 y1 = *(const float4*)&actB[f1 + 64 + i4 * 4];
                    const float4 y2 = *(const float4*)&actB[f2 + 64 + i4 * 4];
#pragma unroll
                    for (int u = 0; u < 4; ++u) {
                        const int row = (i4 * 4 + u) * 128 + colf;
                        const float4 wA = *(const float4*)&wH[row];
                        const float4 wB = *(const float4*)&wH[row + 4];
                        const float v0 = (&y0.x)[u], v1 = (&y1.x)[u], v2 = (&y2.x)[u];
                        a0[0] += v0 * wA.x; a0[1] += v0 * wA.y;
                        a0[2] += v0 * wA.z; a0[3] += v0 * wA.w;
                        a0[4] += v0 * wB.x; a0[5] += v0 * wB.y;
                        a0[6] += v0 * wB.z; a0[7] += v0 * wB.w;
                        a1[0] += v1 * wA.x; a1[1] += v1 * wA.y;
                        a1[2] += v1 * wA.z; a1[3] += v1 * wA.w;
                        a1[4] += v1 * wB.x; a1[5] += v1 * wB.y;
                        a1[6] += v1 * wB.z; a1[7] += v1 * wB.w;
                        a2[0] += v2 * wA.x; a2[1] += v2 * wA.y;
                        a2[2] += v2 * wA.z; a2[3] += v2 * wA.w;
                        a2[4] += v2 * wB.x; a2[5] += v2 * wB.y;
                        a2[6] += v2 * wB.z; a2[7] += v2 * wB.w;
                    }
                }
                const float4 bA = *(const float4*)&wFa[4224 + colf];
                const float4 bB = *(const float4*)&wFa[4224 + colf + 4];
                float4 o0, o1;
                o0.x = lrelu(a0[0] + bA.x); o0.y = lrelu(a0[1] + bA.y);
                o0.z = lrelu(a0[2] + bA.z); o0.w = lrelu(a0[3] + bA.w);
                o1.x = lrelu(a0[4] + bB.x); o1.y = lrelu(a0[5] + bB.y);
                o1.z = lrelu(a0[6] + bB.z); o1.w = lrelu(a0[7] + bB.w);
                *(float4*)&actA[f0 + colf]     = o0;
                *(float4*)&actA[f0 + colf + 4] = o1;
                o0.x = lrelu(a1[0] + bA.x); o0.y = lrelu(a1[1] + bA.y);
                o0.z = lrelu(a1[2] + bA.z); o0.w = lrelu(a1[3] + bA.w);
                o1.x = lrelu(a1[4] + bB.x); o1.y = lrelu(a1[5] + bB.y);
                o1.z = lrelu(a1[6] + bB.z); o1.w = lrelu(a1[7] + bB.w);
                *(float4*)&actA[f1 + colf]     = o0;
                *(float4*)&actA[f1 + colf + 4] = o1;
                o0.x = lrelu(a2[0] + bA.x); o0.y = lrelu(a2[1] + bA.y);
                o0.z = lrelu(a2[2] + bA.z); o0.w = lrelu(a2[3] + bA.w);
                o1.x = lrelu(a2[4] + bB.x); o1.y = lrelu(a2[5] + bB.y);
                o1.z = lrelu(a2[6] + bB.z); o1.w = lrelu(a2[7] + bB.w);
                *(float4*)&actA[f2 + colf]     = o0;
                *(float4*)&actA[f2 + colf + 4] = o1;
            }
        }
        __syncthreads();   // B8

        // ---- f-L3: 128 -> 8 (no act) + sin/cos; 1 batch/thread (t<384) ----
        if (fb3 < CAP) {
            const int ib = pb + fb3;
            if (ib < hi) {
                const int foff = fb3 * FSTRIDE;
                float a = 0.f;
#pragma unroll 8
                for (int i4 = 0; i4 < 32; ++i4) {
                    const float4 y4 = *(const float4*)&actA[foff + i4 * 4];
#pragma unroll
                    for (int u = 0; u < 4; ++u)
                        a += (&y4.x)[u] * wFa[4352 + (i4 * 4 + u) * 8 + col8];
                }
                a += wFa[5376 + col8];
                const int bi = perm[base + ib];
                out[(size_t)bi * 16 + col8]     = __sinf(a);
                out[(size_t)bi * 16 + 8 + col8] = __cosf(a);
            }
        }
    }
}

// ---------------------------------------------------------------------------
extern "C" void kernel_launch(void* const* d_in, const int* in_sizes, int n_in,
                              void* d_out, int out_size, void* d_ws, size_t ws_size,
                              hipStream_t stream)
{
    const int*   indices = (const int*)  d_in[0];
    const float* states  = (const float*)d_in[1];
    const float* maps    = (const float*)d_in[2];
    const float* fc1_w   = (const float*)d_in[3];
    const float* fc1_b   = (const float*)d_in[4];
    const float* fc2_w   = (const float*)d_in[5];
    const float* fc2_b   = (const float*)d_in[6];
    const float* fc3_w   = (const float*)d_in[7];
    const float* fc3_b   = (const float*)d_in[8];
    const float* bn_w    = (const float*)d_in[9];
    const float* bn_b    = (const float*)d_in[10];
    const float* e_w     = (const float*)d_in[11];
    const float* e_b     = (const float*)d_in[12];
    const float* f_w     = (const float*)d_in[13];
    const float* f_b     = (const float*)d_in[14];
    float* out = (float*)d_out;

    float* ws   = (float*)d_ws;
    float* z    = ws;                    // 2048
    float* th_e = ws + 2048;             // 349184
    float* th_f = ws + 351232;           // 1393152
    int* counts  = (int*)(ws + 1744384); // 64
    int* offsets = counts + 64;          // 64
    int* perm    = counts + 128;         // 8192
    float* h1g   = ws + 1752704;         // 16384

    static int s_lds_optin = 0;
    if (!s_lds_optin) {
        hipFuncSetAttribute((const void*)func_kernel,
                            hipFuncAttributeMaxDynamicSharedMemorySize,
                            K3_LDS_BYTES);
        s_lds_optin = 1;
    }

    fc1_kernel<<<256, 1024, 0, stream>>>(maps, fc1_w, fc1_b, h1g);
    backbone_bucket_kernel<<<65, 1024, 0, stream>>>(
        h1g, fc2_w, fc2_b, fc3_w, fc3_b, bn_w, bn_b, z,
        indices, counts, offsets, perm);
    theta_kernel<<<dim3(107, 8), 256, 0, stream>>>(
        z, e_w, e_b, f_w, f_b, th_e, th_f);
    func_kernel<<<dim3(NCLS, 4), 512, K3_LDS_BYTES, stream>>>(
        states, th_e, th_f, counts, offsets, perm, out);
}